// Round 2
// baseline (330.015 us; speedup 1.0000x reference)
//
#include <hip/hip_runtime.h>
#include <hip/hip_bf16.h>
#include <cstdint>
#include <cstddef>

// Problem constants
#define MROWS 8192   // B*L
#define EDIM  1024   // E
#define VDIM  64     // V
#define NTRI  2016   // V*(V-1)/2
#define NTC   2176   // NTRI + 64 (theta logits) padded to 17*128 tiles

typedef _Float16 half8  __attribute__((ext_vector_type(8)));
typedef _Float16 half4v __attribute__((ext_vector_type(4)));
typedef float    floatx4 __attribute__((ext_vector_type(4)));

typedef __attribute__((address_space(1))) void gvoid;
typedef __attribute__((address_space(3))) void svoid;

__device__ inline void gld_lds16(const _Float16* g, _Float16* l) {
    // async global->LDS, 16B per lane; LDS dest = wave-uniform base + lane*16
    __builtin_amdgcn_global_load_lds((gvoid*)g, (svoid*)l, 16, 0, 0);
}

// Fast erf: Abramowitz-Stegun 7.1.26, |err| < 1.5e-7 (hw v_exp_f32)
__device__ inline float fast_erf(float x) {
    float ax = fabsf(x);
    float t = 1.0f / (1.0f + 0.3275911f * ax);
    float p = t * (0.254829592f +
              t * (-0.284496736f +
              t * (1.421413741f +
              t * (-1.453152027f +
              t * 1.061405429f))));
    float r = 1.0f - p * __expf(-ax * ax);
    return copysignf(r, x);
}

// Fast softplus via hw v_exp/v_log; exact identity, stable both tails
__device__ inline float fast_softplus(float x) {
    return fmaxf(x, 0.0f) + __logf(1.0f + __expf(-fabsf(x)));
}

// ---------------- cast fp32 -> fp16 (with zero padding) ----------------
__global__ __launch_bounds__(256) void cast_f2h(const float* __restrict__ in,
                                                _Float16* __restrict__ out,
                                                int n_valid, int n_total) {
    int idx = (blockIdx.x * 256 + threadIdx.x) * 4;
    if (idx >= n_total) return;
    half4v o;
    if (idx < n_valid) {
        float4 v = *(const float4*)(in + idx);
        o[0] = (_Float16)v.x; o[1] = (_Float16)v.y;
        o[2] = (_Float16)v.z; o[3] = (_Float16)v.w;
    } else {
        o[0] = (_Float16)0.f; o[1] = (_Float16)0.f;
        o[2] = (_Float16)0.f; o[3] = (_Float16)0.f;
    }
    *(half4v*)(out + idx) = o;
}

// ---------------- GEMM: C = epilogue(A @ Bt^T), fp16 output ----------------
// A: M x K fp16 row-major, Bt: N x K fp16 row-major (i.e. B transposed)
// 128x128 tile per block, 256 threads (4 waves, 2x2 of 64x64), K-chunk 64.
//
// 2-PHASE double-buffered pipeline (T3 minimum recipe): prologue stages
// buf0; each tile then {issue STAGE(next tile -> other buf), ds_read+MFMA
// current buf, ONE __syncthreads() (drains vmcnt(0)+lgkmcnt, barrier)}.
// Loads for tile t+1 are in flight during compute of tile t.
//
// XCD-aware grid: 1D launch; block b -> xcd = b&7 (HW round-robin), and
// m-tile = xcd + 8*(slot/ntiles_n). All n-blocks of one m-tile run on the
// same XCD -> A-tile fetched from HBM once, then L2-hit.
//
// LDS: rows of 64 halfs (128 B). Slot (r, c) (c = 16B chunk 0..7) holds
// global chunk (c ^ (r&7)); staging permutes the global source within each
// row's 128 B line (global_load_lds LDS dest is lane-order-pinned);
// fragment reads invert -> every 16-lane ds_read_b128 phase is 2-way (free).
//
// MODE 0: gelu(x + bias[gn])                  (dense layer) -> fp16
// MODE 1: gn <  NTRI       -> softplus(x + bias[gn])   (Theta)    -> fp16
//         NTRI <= gn < +64 -> x + bias2[gn-NTRI]       (pi logits, raw)
//         else             -> 0                        (padding)
template <int MODE>
__global__ __launch_bounds__(256) void gemm_bt(const _Float16* __restrict__ A,
                                               const _Float16* __restrict__ Bt,
                                               const float* __restrict__ bias,
                                               const float* __restrict__ bias2,
                                               _Float16* __restrict__ C, int N) {
    __shared__ __align__(16) _Float16 As[2][128 * 64];
    __shared__ __align__(16) _Float16 Bs[2][128 * 64];

    const int tid  = threadIdx.x;
    // XCD-aware tile mapping
    const int ng   = N >> 7;             // n-tiles (17 or 8)
    const int xcd  = blockIdx.x & 7;
    const int slot = blockIdx.x >> 3;
    const int mg   = slot / ng;
    const int nn   = slot - mg * ng;
    const int m0   = (xcd + mg * 8) * 128;
    const int n0   = nn * 128;

    const int w    = tid >> 6;
    const int lane = tid & 63;
    const int wr   = w >> 1;             // wave row (0..1) -> 64 rows
    const int wc   = w & 1;              // wave col (0..1) -> 64 cols
    const int lrow  = lane & 15;         // m (A) / n (B) within 16
    const int lquad = lane >> 4;         // k-group (8 elems each)

    floatx4 acc[4][4] = {};

    // staging: thread t -> tile row r0 = t>>3 (+32 per call), chunk c0 = t&7.
    // LDS dest (pinned) = slot (r0, c0); global source chunk g = c0 ^ (r0&7).
    const int r0 = tid >> 3;             // 0..31
    const int c0 = tid & 7;
    const int g  = (c0 ^ (r0 & 7)) * 8;  // halfs offset within row's 64
    const _Float16* Ag[4];
    const _Float16* Bg[4];
#pragma unroll
    for (int call = 0; call < 4; ++call) {
        Ag[call] = A  + (size_t)(m0 + call * 32 + r0) * EDIM + g;
        Bg[call] = Bt + (size_t)(n0 + call * 32 + r0) * EDIM + g;
    }

    const int swr = lrow & 7;

    auto stage = [&](int buf, int koff) {
        _Float16* aD = &As[buf][tid * 8];    // call c adds c*2048 halfs
        _Float16* bD = &Bs[buf][tid * 8];
#pragma unroll
        for (int call = 0; call < 4; ++call) {
            gld_lds16(Ag[call] + koff, aD + call * 2048);
            gld_lds16(Bg[call] + koff, bD + call * 2048);
        }
    };
    auto compute = [&](int buf) {
        // fragment read bases: row = wr*64 + i*16 + lrow (64 halfs per row)
        const _Float16* ardA = &As[buf][(wr * 64 + lrow) * 64];
        const _Float16* brdB = &Bs[buf][(wc * 64 + lrow) * 64];
#pragma unroll
        for (int kstep = 0; kstep < 2; ++kstep) {
            const int soff = ((kstep * 4 + lquad) ^ swr) * 8;
            half8 af[4], bf[4];
#pragma unroll
            for (int t = 0; t < 4; ++t) {
                af[t] = *(const half8*)(ardA + t * 16 * 64 + soff);
                bf[t] = *(const half8*)(brdB + t * 16 * 64 + soff);
            }
#pragma unroll
            for (int i = 0; i < 4; ++i)
#pragma unroll
                for (int j = 0; j < 4; ++j)
                    acc[i][j] = __builtin_amdgcn_mfma_f32_16x16x32_f16(
                        af[i], bf[j], acc[i][j], 0, 0, 0);
        }
    };

    // -------- 2-phase pipelined K-loop (16 tiles of 64, EDIM/64 even) ------
    stage(0, 0);
    __syncthreads();                       // buf0 ready
#pragma unroll 1
    for (int k0 = 0; k0 < EDIM; k0 += 128) {
        stage(1, k0 + 64);                 // prefetch odd tile (always valid)
        compute(0);
        __syncthreads();                   // drains vmcnt(0) -> buf1 ready
        if (k0 + 128 < EDIM) stage(0, k0 + 128);  // prefetch next even tile
        compute(1);
        __syncthreads();                   // drains vmcnt(0) -> buf0 ready
    }

    // Epilogue. C/D layout (m89-verified): col = lane&15, row = (lane>>4)*4 + reg
    const int cm = m0 + wr * 64 + lquad * 4;
    const int cn = n0 + wc * 64 + lrow;
#pragma unroll
    for (int j = 0; j < 4; ++j) {
        const int gn = cn + j * 16;
        float bv;
        if (MODE == 0) {
            bv = bias[gn];
        } else {
            // gn-groups are 16-aligned and NTRI/NTRI+64 are multiples of 16,
            // so these branches are wave-subgroup-uniform.
            if (gn < NTRI)             bv = bias[gn];
            else if (gn < NTRI + VDIM) bv = bias2[gn - NTRI];
            else                       bv = 0.0f;
        }
#pragma unroll
        for (int i = 0; i < 4; ++i) {
#pragma unroll
            for (int r = 0; r < 4; ++r) {
                float x = acc[i][j][r] + bv;
                float y;
                if (MODE == 0) {
                    y = 0.5f * x * (1.0f + fast_erf(x * 0.70710678118654752f));
                } else {
                    if (gn < NTRI) {
                        y = fast_softplus(x);
                    } else if (gn < NTRI + VDIM) {
                        y = x;             // raw pi logit
                    } else {
                        y = 0.0f;          // padding
                    }
                }
                C[(size_t)(cm + i * 16 + r) * N + gn] = (_Float16)y;
            }
        }
    }
}

// ---------------- LayerNorm: fp16 G in -> fp16 Hh out (no fp32 writeback) ----
__global__ __launch_bounds__(256) void ln_kernel(const _Float16* __restrict__ G,
                                                 const float* __restrict__ gw,
                                                 const float* __restrict__ bw,
                                                 _Float16* __restrict__ Hh) {
    const int row = blockIdx.x, tid = threadIdx.x;
    half4v v = ((const half4v*)(G + (size_t)row * EDIM))[tid];
    float x0 = (float)v[0], x1 = (float)v[1], x2 = (float)v[2], x3 = (float)v[3];
    float s  = x0 + x1 + x2 + x3;
    float ss = x0 * x0 + x1 * x1 + x2 * x2 + x3 * x3;
#pragma unroll
    for (int off = 32; off; off >>= 1) {
        s  += __shfl_down(s, off);
        ss += __shfl_down(ss, off);
    }
    __shared__ float red[8];
    const int w = tid >> 6, lane = tid & 63;
    if (lane == 0) { red[w] = s; red[4 + w] = ss; }
    __syncthreads();
    const float st  = red[0] + red[1] + red[2] + red[3];
    const float sst = red[4] + red[5] + red[6] + red[7];
    const float mu  = st * (1.0f / EDIM);
    const float rs  = 1.0f / sqrtf(sst * (1.0f / EDIM) - mu * mu + 1e-5f);
    float4 gg = ((const float4*)gw)[tid];
    float4 bb = ((const float4*)bw)[tid];
    half4v h4;
    h4[0] = (_Float16)((x0 - mu) * rs * gg.x + bb.x);
    h4[1] = (_Float16)((x1 - mu) * rs * gg.y + bb.y);
    h4[2] = (_Float16)((x2 - mu) * rs * gg.z + bb.z);
    h4[3] = (_Float16)((x3 - mu) * rs * gg.w + bb.w);
    ((half4v*)(Hh + (size_t)row * EDIM))[tid] = h4;
}

// ---------------- Q build + fused softmax: one block per (b,l) row ---------
// Wave 3 computes softmax over the 64 logit columns (Theta[NTRI..NTRI+64))
// -> pi_out + sqrt(pi) in LDS, while threads 0..251 stage the 2016 Theta
// values (half8 loads, fp32 in LDS). Then:
// Q[i][j] = Theta[tri(i,j)] * sp[j]/sp[i] (i!=j), Q[i][i] = -rowsum (folded
// into the vectorized store).
__global__ __launch_bounds__(256) void q_kernel(const _Float16* __restrict__ Theta,
                                                float* __restrict__ pi_out,
                                                float* __restrict__ Q) {
    const int row = blockIdx.x;
    const int tid = threadIdx.x;
    __shared__ float Th[NTRI];
    __shared__ float spv[VDIM];
    const _Float16* trow = Theta + (size_t)row * NTC;
    if (tid < 252) {  // 252 * 8 = 2016 = NTRI exactly
        half8 h = *(const half8*)(trow + tid * 8);
#pragma unroll
        for (int u = 0; u < 8; ++u) Th[tid * 8 + u] = (float)h[u];
    }
    if (tid >= 192) {  // wave 3: softmax over the 64 logits
        const int lane = tid & 63;
        float lg = (float)trow[NTRI + lane];
        float m = lg;
#pragma unroll
        for (int off = 32; off; off >>= 1) m = fmaxf(m, __shfl_xor(m, off));
        float e = __expf(lg - m);
        float ssum = e;
#pragma unroll
        for (int off = 32; off; off >>= 1) ssum += __shfl_xor(ssum, off);
        float p = e / ssum;
        pi_out[(size_t)row * VDIM + lane] = p;
        spv[lane] = sqrtf(p);
    }
    __syncthreads();

    const int i = tid >> 2;   // Q row 0..63
    const int q = tid & 3;    // col quarter
    const float rpi = 1.0f / spv[i];
    float vals[16];
    float psum = 0.f;
#pragma unroll
    for (int c = 0; c < 16; ++c) {
        const int j = q * 16 + c;
        float out = 0.f;
        if (j != i) {
            const int a = (i < j) ? i : j;
            const int b = (i < j) ? j : i;
            const int t = a * (127 - a) / 2 + (b - a - 1);
            out = Th[t] * spv[j] * rpi;
            psum += out;
        }
        vals[c] = out;
    }
    // full rowsum across the 4 consecutive lanes of this row
    psum += __shfl_xor(psum, 1);
    psum += __shfl_xor(psum, 2);
    if ((i >> 4) == q) vals[i & 15] = -psum;   // fold diagonal into the store

    float* qrow = Q + ((size_t)row * VDIM + i) * VDIM + q * 16;
    float4* dst = (float4*)qrow;
    dst[0] = make_float4(vals[0], vals[1], vals[2], vals[3]);
    dst[1] = make_float4(vals[4], vals[5], vals[6], vals[7]);
    dst[2] = make_float4(vals[8], vals[9], vals[10], vals[11]);
    dst[3] = make_float4(vals[12], vals[13], vals[14], vals[15]);
}

// ---------------- orchestration ----------------
extern "C" void kernel_launch(void* const* d_in, const int* in_sizes, int n_in,
                              void* d_out, int out_size, void* d_ws, size_t ws_size,
                              hipStream_t stream) {
    const float* hx      = (const float*)d_in[0];
    const float* W_dense = (const float*)d_in[1];
    const float* b_dense = (const float*)d_in[2];
    const float* ln_g    = (const float*)d_in[3];
    const float* ln_b    = (const float*)d_in[4];
    const float* W_theta = (const float*)d_in[5];
    const float* b_theta = (const float*)d_in[6];
    const float* W_Theta = (const float*)d_in[7];
    const float* b_Theta = (const float*)d_in[8];

    uint8_t* ws = (uint8_t*)d_ws;
    // ws layout (~59 MB peak):
    _Float16* A_h  = (_Float16*)ws;                          // 16 MB (hx fp16; later h fp16)
    _Float16* Wd_h = (_Float16*)(ws + (size_t)16 * 1048576); //  2 MB
    _Float16* Wc_h = (_Float16*)(ws + (size_t)18 * 1048576); //  4.25 MB (2176x1024: W_Theta|W_theta|0)
    _Float16* G_h  = (_Float16*)(ws + (size_t)23 * 1048576); // 16 MB (gelu out, fp16)
    _Float16* Th_h = (_Float16*)(ws + (size_t)23 * 1048576); // 35.7 MB (8192x2176 fp16) — reuses G after LN

    float* Q_out  = (float*)d_out;                 // 8192*64*64
    float* pi_out = (float*)d_out + (size_t)MROWS * VDIM * VDIM;

    // 1) casts to fp16; combined theta weight = [W_Theta ; W_theta ; zeros]
    cast_f2h<<<(MROWS * EDIM / 4) / 256, 256, 0, stream>>>(hx, A_h, MROWS * EDIM, MROWS * EDIM);
    cast_f2h<<<(EDIM * EDIM / 4) / 256, 256, 0, stream>>>(W_dense, Wd_h, EDIM * EDIM, EDIM * EDIM);
    cast_f2h<<<(NTRI * EDIM / 4) / 256, 256, 0, stream>>>(W_Theta, Wc_h, NTRI * EDIM, NTRI * EDIM);
    cast_f2h<<<((NTC - NTRI) * EDIM / 4) / 256, 256, 0, stream>>>(
        W_theta, Wc_h + (size_t)NTRI * EDIM, VDIM * EDIM, (NTC - NTRI) * EDIM);

    // 2) dense GEMM + gelu -> G_h (fp16)  (1D grid, XCD-aware mapping inside)
    gemm_bt<0><<<(EDIM / 128) * (MROWS / 128), 256, 0, stream>>>(
        A_h, Wd_h, b_dense, nullptr, G_h, EDIM);

    // 3) LayerNorm: fp16 G -> fp16 h into A_h (hx fp16 no longer needed)
    ln_kernel<<<MROWS, 256, 0, stream>>>(G_h, ln_g, ln_b, A_h);

    // 4) combined Theta+logits GEMM (softplus / raw epilogue) -> Th_h fp16
    //    (overwrites G_h, which is dead after ln_kernel)
    gemm_bt<1><<<(NTC / 128) * (MROWS / 128), 256, 0, stream>>>(
        A_h, Wc_h, b_Theta, b_theta, Th_h, NTC);

    // 5) Q assembly + fused softmax (pi, sqrt(pi) computed in-kernel)
    q_kernel<<<MROWS, 256, 0, stream>>>(Th_h, pi_out, Q_out);
}

// Round 3
// 325.020 us; speedup vs baseline: 1.0154x; 1.0154x over previous
//
#include <hip/hip_runtime.h>
#include <hip/hip_bf16.h>
#include <cstdint>
#include <cstddef>

// Problem constants
#define MROWS 8192   // B*L
#define EDIM  1024   // E
#define VDIM  64     // V
#define NTRI  2016   // V*(V-1)/2
#define NTC   2176   // NTRI + 64 (theta logits) padded to 17*128 tiles

typedef _Float16 half8  __attribute__((ext_vector_type(8)));
typedef _Float16 half4v __attribute__((ext_vector_type(4)));
typedef float    floatx4 __attribute__((ext_vector_type(4)));

typedef __attribute__((address_space(1))) void gvoid;
typedef __attribute__((address_space(3))) void svoid;

__device__ inline void gld_lds16(const _Float16* g, _Float16* l) {
    // async global->LDS, 16B per lane; LDS dest = wave-uniform base + lane*16
    __builtin_amdgcn_global_load_lds((gvoid*)g, (svoid*)l, 16, 0, 0);
}

#define BAR() do { asm volatile("" ::: "memory"); \
                   __builtin_amdgcn_s_barrier();  \
                   asm volatile("" ::: "memory"); } while (0)

// Fast erf: Abramowitz-Stegun 7.1.26, |err| < 1.5e-7 (hw v_exp_f32)
__device__ inline float fast_erf(float x) {
    float ax = fabsf(x);
    float t = 1.0f / (1.0f + 0.3275911f * ax);
    float p = t * (0.254829592f +
              t * (-0.284496736f +
              t * (1.421413741f +
              t * (-1.453152027f +
              t * 1.061405429f))));
    float r = 1.0f - p * __expf(-ax * ax);
    return copysignf(r, x);
}

// Fast softplus via hw v_exp/v_log; exact identity, stable both tails
__device__ inline float fast_softplus(float x) {
    return fmaxf(x, 0.0f) + __logf(1.0f + __expf(-fabsf(x)));
}

// ---------------- cast fp32 -> fp16 (with zero padding) ----------------
__global__ __launch_bounds__(256) void cast_f2h(const float* __restrict__ in,
                                                _Float16* __restrict__ out,
                                                int n_valid, int n_total) {
    int idx = (blockIdx.x * 256 + threadIdx.x) * 4;
    if (idx >= n_total) return;
    half4v o;
    if (idx < n_valid) {
        float4 v = *(const float4*)(in + idx);
        o[0] = (_Float16)v.x; o[1] = (_Float16)v.y;
        o[2] = (_Float16)v.z; o[3] = (_Float16)v.w;
    } else {
        o[0] = (_Float16)0.f; o[1] = (_Float16)0.f;
        o[2] = (_Float16)0.f; o[3] = (_Float16)0.f;
    }
    *(half4v*)(out + idx) = o;
}

// ---------------- GEMM: C = epilogue(A @ Bt^T), fp16 output ----------------
// 256 x BN tile (BN = NF*64), 512 threads = 8 waves (2m x 4n), BK=32.
// 4-deep LDS pipeline with counted vmcnt (T3+T4): while computing K-tile t,
// stage K-tile t+3; tile boundary waits vmcnt(2L) (L loads/thread/tile) --
// NEVER vmcnt(0) in the main loop. Raw s_barrier (no compiler drain).
// setprio(1) around MFMA clusters (T5; pays with phase-split, m218b).
//
// LDS layout per buffer: A = 256 rows x 32 halfs (64B rows), B = BN rows.
// Swizzle: slot (row r, 16B-chunk c) holds global chunk c ^ ((r>>1)&3);
// staging pre-swizzles the per-lane GLOBAL source (dest lane-pinned linear);
// reads invert. 16-lane b128 column reads spread 2-way over banks (free).
//
// Grid: 1D, b -> xcd = b&7, slot = b>>3, n = slot % ntg, m = xcd + 8*(slot/ntg).
// Same-m blocks land on one XCD -> A-slab L2 reuse.
//
// MODE 0: gelu(x + bias[gn]); MODE 1: softplus / raw-logit / zero by column.
template <int MODE, int NF>   // NF = n-frags per wave: 4 -> BN=256, 2 -> BN=128
__global__ __launch_bounds__(512, 2) void gemm25(const _Float16* __restrict__ A,
                                                 const _Float16* __restrict__ Bt,
                                                 const float* __restrict__ bias,
                                                 const float* __restrict__ bias2,
                                                 _Float16* __restrict__ C,
                                                 int ldC, int col0, int ntg) {
    constexpr int BN = NF * 64;
    constexpr int WN = NF * 16;            // per-wave col span
    constexpr int BHALF = 8192 + BN * 32;  // halfs per buffer (A 16KB + B)
    constexpr int NT = EDIM / 32;          // 32 K-tiles
    __shared__ __align__(16) _Float16 S[4][BHALF];

    const int tid  = threadIdx.x;
    const int xcd  = blockIdx.x & 7;
    const int slot = blockIdx.x >> 3;
    const int nn   = slot % ntg;
    const int mg   = slot / ntg;
    const int m0   = (xcd + mg * 8) * 256;
    const int n0   = nn * BN;

    const int w = tid >> 6, lane = tid & 63;
    const int wr = w >> 2;                 // 0..1 -> 128 rows
    const int wc = w & 3;                  // 0..3 -> WN cols
    const int lrow = lane & 15, lquad = lane >> 4;

    floatx4 acc[8][NF] = {};

    // ---- staging geometry: thread t -> slot row R = t>>2 (+128), chunk c0 = t&3
    const int R  = tid >> 2;               // 0..127
    const int c0 = tid & 3;
    const int gk = (c0 ^ ((R >> 1) & 3)) * 8;   // swizzled global k-offset (halfs)
    const _Float16* Ag0 = A  + (size_t)(m0 + R) * EDIM + gk;
    const _Float16* Ag1 = Ag0 + (size_t)128 * EDIM;
    const _Float16* Bg0 = Bt + (size_t)(col0 + n0 + R) * EDIM + gk;
    const _Float16* Bg1 = Bg0 + (size_t)128 * EDIM;  // used only when NF==4

    // constexpr loads/thread/tile: NF==4 -> 4 (A2+B2), NF==2 -> 3 (A2+B1)
    // ---- read geometry: chunk xor depends only on lrow
    const int xr   = (lrow >> 1) & 3;
    const int koff = (lquad ^ xr) * 8;
    const int aoff = (wr * 128 + lrow) * 32 + koff;          // frag i adds i*512
    const int boff = 8192 + (wc * WN + lrow) * 32 + koff;    // frag j adds j*512

    // ---- prologue: stage tiles 0,1,2 (order matters for vmcnt math)
#pragma unroll
    for (int t = 0; t < 3; ++t) {
        _Float16* d = &S[t][tid * 8];
        gld_lds16(Ag0 + t * 32, d);
        gld_lds16(Ag1 + t * 32, d + 4096);
        gld_lds16(Bg0 + t * 32, d + 8192);
        if constexpr (NF == 4) gld_lds16(Bg1 + t * 32, d + 12288);
    }
    if constexpr (NF == 4) asm volatile("s_waitcnt vmcnt(8)" ::: "memory");
    else                   asm volatile("s_waitcnt vmcnt(6)" ::: "memory");
    BAR();                                 // tile 0 ready for all threads

#pragma unroll 1
    for (int t = 0; t < NT; ++t) {
        const int buf = t & 3;
        const _Float16* Sb = S[buf];
        const bool doStage = (t + 3 < NT);
        const int sb = (t + 3) & 3;
        const int sk = (t + 3) * 32;

        half8 bf[NF], af[4];
        // ---- phase 0: bf (all NF) + af mfrags 0..3; stage next A
#pragma unroll
        for (int j = 0; j < NF; ++j) bf[j] = *(const half8*)(Sb + boff + j * 512);
#pragma unroll
        for (int i = 0; i < 4; ++i)  af[i] = *(const half8*)(Sb + aoff + i * 512);
        if (doStage) {
            _Float16* d = &S[sb][tid * 8];
            gld_lds16(Ag0 + sk, d);
            gld_lds16(Ag1 + sk, d + 4096);
        }
        BAR();
        __builtin_amdgcn_s_setprio(1);
#pragma unroll
        for (int i = 0; i < 4; ++i)
#pragma unroll
            for (int j = 0; j < NF; ++j)
                acc[i][j] = __builtin_amdgcn_mfma_f32_16x16x32_f16(
                    af[i], bf[j], acc[i][j], 0, 0, 0);
        __builtin_amdgcn_s_setprio(0);
        BAR();

        // ---- phase 1: af mfrags 4..7; stage next B
#pragma unroll
        for (int i = 0; i < 4; ++i)
            af[i] = *(const half8*)(Sb + aoff + 2048 + i * 512);
        if (doStage) {
            _Float16* d = &S[sb][tid * 8];
            gld_lds16(Bg0 + sk, d + 8192);
            if constexpr (NF == 4) gld_lds16(Bg1 + sk, d + 12288);
        }
        BAR();
        __builtin_amdgcn_s_setprio(1);
#pragma unroll
        for (int i = 0; i < 4; ++i)
#pragma unroll
            for (int j = 0; j < NF; ++j)
                acc[4 + i][j] = __builtin_amdgcn_mfma_f32_16x16x32_f16(
                    af[i], bf[j], acc[4 + i][j], 0, 0, 0);
        __builtin_amdgcn_s_setprio(0);

        // ---- tile boundary: counted wait (tile t+1 must be resident)
        if (t < NT - 3) {
            if constexpr (NF == 4) asm volatile("s_waitcnt vmcnt(8)" ::: "memory");
            else                   asm volatile("s_waitcnt vmcnt(6)" ::: "memory");
        } else if (t == NT - 3) {
            if constexpr (NF == 4) asm volatile("s_waitcnt vmcnt(4)" ::: "memory");
            else                   asm volatile("s_waitcnt vmcnt(3)" ::: "memory");
        } else if (t == NT - 2) {
            asm volatile("s_waitcnt vmcnt(0)" ::: "memory");
        }
        BAR();
    }

    // Epilogue. C/D layout (m89-verified): col = lane&15, row = (lane>>4)*4 + reg
    const int cmb = m0 + wr * 128 + lquad * 4;
    const int cnb = col0 + n0 + wc * WN + lrow;
#pragma unroll
    for (int j = 0; j < NF; ++j) {
        const int gn = cnb + j * 16;
        float bv;
        if (MODE == 0) {
            bv = bias[gn];
        } else {
            // 16-aligned column groups; NTRI, NTRI+64 are multiples of 16
            if (gn < NTRI)             bv = bias[gn];
            else if (gn < NTRI + VDIM) bv = bias2[gn - NTRI];
            else                       bv = 0.0f;
        }
#pragma unroll
        for (int i = 0; i < 8; ++i) {
#pragma unroll
            for (int r = 0; r < 4; ++r) {
                float x = acc[i][j][r] + bv;
                float y;
                if (MODE == 0) {
                    y = 0.5f * x * (1.0f + fast_erf(x * 0.70710678118654752f));
                } else {
                    if (gn < NTRI)             y = fast_softplus(x);
                    else if (gn < NTRI + VDIM) y = x;      // raw pi logit
                    else                       y = 0.0f;   // padding
                }
                C[(size_t)(cmb + i * 16 + r) * ldC + gn] = (_Float16)y;
            }
        }
    }
}

// ---------------- LayerNorm: fp16 G in -> fp16 Hh out ----------------
__global__ __launch_bounds__(256) void ln_kernel(const _Float16* __restrict__ G,
                                                 const float* __restrict__ gw,
                                                 const float* __restrict__ bw,
                                                 _Float16* __restrict__ Hh) {
    const int row = blockIdx.x, tid = threadIdx.x;
    half4v v = ((const half4v*)(G + (size_t)row * EDIM))[tid];
    float x0 = (float)v[0], x1 = (float)v[1], x2 = (float)v[2], x3 = (float)v[3];
    float s  = x0 + x1 + x2 + x3;
    float ss = x0 * x0 + x1 * x1 + x2 * x2 + x3 * x3;
#pragma unroll
    for (int off = 32; off; off >>= 1) {
        s  += __shfl_down(s, off);
        ss += __shfl_down(ss, off);
    }
    __shared__ float red[8];
    const int w = tid >> 6, lane = tid & 63;
    if (lane == 0) { red[w] = s; red[4 + w] = ss; }
    __syncthreads();
    const float st  = red[0] + red[1] + red[2] + red[3];
    const float sst = red[4] + red[5] + red[6] + red[7];
    const float mu  = st * (1.0f / EDIM);
    const float rs  = 1.0f / sqrtf(sst * (1.0f / EDIM) - mu * mu + 1e-5f);
    float4 gg = ((const float4*)gw)[tid];
    float4 bb = ((const float4*)bw)[tid];
    half4v h4;
    h4[0] = (_Float16)((x0 - mu) * rs * gg.x + bb.x);
    h4[1] = (_Float16)((x1 - mu) * rs * gg.y + bb.y);
    h4[2] = (_Float16)((x2 - mu) * rs * gg.z + bb.z);
    h4[3] = (_Float16)((x3 - mu) * rs * gg.w + bb.w);
    ((half4v*)(Hh + (size_t)row * EDIM))[tid] = h4;
}

// ---------------- Q build + fused softmax: one block per (b,l) row ---------
__global__ __launch_bounds__(256) void q_kernel(const _Float16* __restrict__ Theta,
                                                float* __restrict__ pi_out,
                                                float* __restrict__ Q) {
    const int row = blockIdx.x;
    const int tid = threadIdx.x;
    __shared__ float Th[NTRI];
    __shared__ float spv[VDIM];
    const _Float16* trow = Theta + (size_t)row * NTC;
    if (tid < 252) {  // 252 * 8 = 2016 = NTRI exactly
        half8 h = *(const half8*)(trow + tid * 8);
#pragma unroll
        for (int u = 0; u < 8; ++u) Th[tid * 8 + u] = (float)h[u];
    }
    if (tid >= 192) {  // wave 3: softmax over the 64 logits
        const int lane = tid & 63;
        float lg = (float)trow[NTRI + lane];
        float m = lg;
#pragma unroll
        for (int off = 32; off; off >>= 1) m = fmaxf(m, __shfl_xor(m, off));
        float e = __expf(lg - m);
        float ssum = e;
#pragma unroll
        for (int off = 32; off; off >>= 1) ssum += __shfl_xor(ssum, off);
        float p = e / ssum;
        pi_out[(size_t)row * VDIM + lane] = p;
        spv[lane] = sqrtf(p);
    }
    __syncthreads();

    const int i = tid >> 2;   // Q row 0..63
    const int q = tid & 3;    // col quarter
    const float rpi = 1.0f / spv[i];
    float vals[16];
    float psum = 0.f;
#pragma unroll
    for (int c = 0; c < 16; ++c) {
        const int j = q * 16 + c;
        float out = 0.f;
        if (j != i) {
            const int a = (i < j) ? i : j;
            const int b = (i < j) ? j : i;
            const int t = a * (127 - a) / 2 + (b - a - 1);
            out = Th[t] * spv[j] * rpi;
            psum += out;
        }
        vals[c] = out;
    }
    psum += __shfl_xor(psum, 1);
    psum += __shfl_xor(psum, 2);
    if ((i >> 4) == q) vals[i & 15] = -psum;   // fold diagonal into the store

    float* qrow = Q + ((size_t)row * VDIM + i) * VDIM + q * 16;
    float4* dst = (float4*)qrow;
    dst[0] = make_float4(vals[0], vals[1], vals[2], vals[3]);
    dst[1] = make_float4(vals[4], vals[5], vals[6], vals[7]);
    dst[2] = make_float4(vals[8], vals[9], vals[10], vals[11]);
    dst[3] = make_float4(vals[12], vals[13], vals[14], vals[15]);
}

// ---------------- orchestration ----------------
extern "C" void kernel_launch(void* const* d_in, const int* in_sizes, int n_in,
                              void* d_out, int out_size, void* d_ws, size_t ws_size,
                              hipStream_t stream) {
    const float* hx      = (const float*)d_in[0];
    const float* W_dense = (const float*)d_in[1];
    const float* b_dense = (const float*)d_in[2];
    const float* ln_g    = (const float*)d_in[3];
    const float* ln_b    = (const float*)d_in[4];
    const float* W_theta = (const float*)d_in[5];
    const float* b_theta = (const float*)d_in[6];
    const float* W_Theta = (const float*)d_in[7];
    const float* b_Theta = (const float*)d_in[8];

    uint8_t* ws = (uint8_t*)d_ws;
    _Float16* A_h  = (_Float16*)ws;                          // 16 MB (hx fp16; later h fp16)
    _Float16* Wd_h = (_Float16*)(ws + (size_t)16 * 1048576); //  2 MB
    _Float16* Wc_h = (_Float16*)(ws + (size_t)18 * 1048576); //  4.25 MB (2176x1024)
    _Float16* G_h  = (_Float16*)(ws + (size_t)23 * 1048576); // 16 MB (gelu out, fp16)
    _Float16* Th_h = (_Float16*)(ws + (size_t)23 * 1048576); // 35.7 MB (8192x2176 fp16)

    float* Q_out  = (float*)d_out;                 // 8192*64*64
    float* pi_out = (float*)d_out + (size_t)MROWS * VDIM * VDIM;

    // 1) casts to fp16; combined theta weight = [W_Theta ; W_theta ; zeros]
    cast_f2h<<<(MROWS * EDIM / 4) / 256, 256, 0, stream>>>(hx, A_h, MROWS * EDIM, MROWS * EDIM);
    cast_f2h<<<(EDIM * EDIM / 4) / 256, 256, 0, stream>>>(W_dense, Wd_h, EDIM * EDIM, EDIM * EDIM);
    cast_f2h<<<(NTRI * EDIM / 4) / 256, 256, 0, stream>>>(W_Theta, Wc_h, NTRI * EDIM, NTRI * EDIM);
    cast_f2h<<<((NTC - NTRI) * EDIM / 4) / 256, 256, 0, stream>>>(
        W_theta, Wc_h + (size_t)NTRI * EDIM, VDIM * EDIM, (NTC - NTRI) * EDIM);

    // 2) dense GEMM + gelu -> G_h.  256x128 tiles: 32m x 8n = 256 blocks (1/CU)
    gemm25<0, 2><<<256, 512, 0, stream>>>(A_h, Wd_h, b_dense, nullptr, G_h, EDIM, 0, 8);

    // 3) LayerNorm: fp16 G -> fp16 h into A_h
    ln_kernel<<<MROWS, 256, 0, stream>>>(G_h, ln_g, ln_b, A_h);

    // 4) theta GEMM, cols [0,2048): 256x256 tiles: 32m x 8n = 256 blocks (1/CU)
    gemm25<1, 4><<<256, 512, 0, stream>>>(A_h, Wc_h, b_Theta, b_theta, Th_h, NTC, 0, 8);
    //    theta strip, cols [2048,2176): 256x128 tiles: 32m x 1n = 32 blocks
    gemm25<1, 2><<<32, 512, 0, stream>>>(A_h, Wc_h, b_Theta, b_theta, Th_h, NTC, 2048, 1);

    // 5) Q assembly + fused softmax
    q_kernel<<<MROWS, 256, 0, stream>>>(Th_h, pi_out, Q_out);
}

// Round 5
// 307.696 us; speedup vs baseline: 1.0725x; 1.0563x over previous
//
#include <hip/hip_runtime.h>
#include <hip/hip_bf16.h>
#include <cstdint>
#include <cstddef>

// Problem constants
#define MROWS 8192   // B*L
#define EDIM  1024   // E
#define VDIM  64     // V
#define NTRI  2016   // V*(V-1)/2
#define NTC   2176   // NTRI + 64 (theta logits) padded to 17*128 tiles

typedef _Float16 half8  __attribute__((ext_vector_type(8)));
typedef _Float16 half4v __attribute__((ext_vector_type(4)));
typedef float    floatx4 __attribute__((ext_vector_type(4)));

typedef __attribute__((address_space(1))) void gvoid;
typedef __attribute__((address_space(3))) void svoid;

__device__ inline void gld_lds16(const _Float16* g, _Float16* l) {
    // async global->LDS, 16B per lane; LDS dest = wave-uniform base + lane*16
    __builtin_amdgcn_global_load_lds((gvoid*)g, (svoid*)l, 16, 0, 0);
}

// Fast erf: Abramowitz-Stegun 7.1.26, |err| < 1.5e-7 (hw v_exp_f32)
__device__ inline float fast_erf(float x) {
    float ax = fabsf(x);
    float t = 1.0f / (1.0f + 0.3275911f * ax);
    float p = t * (0.254829592f +
              t * (-0.284496736f +
              t * (1.421413741f +
              t * (-1.453152027f +
              t * 1.061405429f))));
    float r = 1.0f - p * __expf(-ax * ax);
    return copysignf(r, x);
}

// Fast softplus via hw v_exp/v_log; exact identity, stable both tails
__device__ inline float fast_softplus(float x) {
    return fmaxf(x, 0.0f) + __logf(1.0f + __expf(-fabsf(x)));
}

// ---------------- single fused cast fp32 -> fp16 (3 segments) ----------------
// blocks [0,8192): hx -> A_h           (8192*1024 elems)
// blocks [8192,9216): W_dense -> Wd_h  (1024*1024)
// blocks [9216,11392): [W_Theta ; W_theta ; zeros] -> Wc_h (2176*1024)
__global__ __launch_bounds__(256) void cast_all(const float* __restrict__ hx,
                                                const float* __restrict__ Wd,
                                                const float* __restrict__ WT,
                                                const float* __restrict__ wt,
                                                _Float16* __restrict__ A_h,
                                                _Float16* __restrict__ Wd_h,
                                                _Float16* __restrict__ Wc_h) {
    const int b = blockIdx.x;
    float4 v;
    _Float16* dst;
    int idx;
    if (b < 8192) {
        idx = (b * 256 + threadIdx.x) * 4;
        v = *(const float4*)(hx + idx);
        dst = A_h;
    } else if (b < 9216) {
        idx = ((b - 8192) * 256 + threadIdx.x) * 4;
        v = *(const float4*)(Wd + idx);
        dst = Wd_h;
    } else {
        idx = ((b - 9216) * 256 + threadIdx.x) * 4;
        if (idx < NTRI * EDIM)                  v = *(const float4*)(WT + idx);
        else if (idx < (NTRI + VDIM) * EDIM)    v = *(const float4*)(wt + (idx - NTRI * EDIM));
        else                                    v = make_float4(0.f, 0.f, 0.f, 0.f);
        dst = Wc_h;
    }
    half4v o;
    o[0] = (_Float16)v.x; o[1] = (_Float16)v.y;
    o[2] = (_Float16)v.z; o[3] = (_Float16)v.w;
    *(half4v*)(dst + idx) = o;
}

// ---------------- GEMM: C = epilogue(A @ Bt^T), fp16 output ----------------
// R1 geometry (proven: 108 VGPR, high TLP): 128x128 tile, 256 threads
// (4 waves, 2x2 of 64x64), K-tile 32.  NEW: 3-deep LDS pipeline with
// counted vmcnt (T4) + raw s_barrier -- the main loop NEVER drains vmcnt
// to 0 (except once at t=NT-2); tile t+2 is staged while tile t computes.
// 3 buffers x 16 KB = 48 KB LDS -> 3 blocks/CU (12 waves/CU) under
// __launch_bounds__(256,3); VGPR ~130, no spill.
//
// LDS per buffer: A = 128 rows x 32 halfs (64 B rows), B same, A at 0,
// B at halfs 4096.  Swizzle: slot (row r, 16B-chunk c in 0..3) holds global
// chunk c ^ ((r>>1)&3); staging pre-swizzles the per-lane GLOBAL source
// (LDS dest lane-pinned linear, rule 21); reads invert.  16-lane b128
// column reads then spread over banks 2-way (free, m136).
//
// Grid 1D: xcd = b&7, slot = b>>3, m-tile = xcd + 8*(slot/ntg), n = slot%ntg.
// All n-blocks of one m-tile share an XCD -> A-slab L2 reuse.
//
// MODE 0: gelu(x + bias[gn]); MODE 1: softplus / raw-logit / zero by column.
template <int MODE>
__global__ __launch_bounds__(256, 3) void gemm128(const _Float16* __restrict__ A,
                                                  const _Float16* __restrict__ Bt,
                                                  const float* __restrict__ bias,
                                                  const float* __restrict__ bias2,
                                                  _Float16* __restrict__ C,
                                                  int ldC, int ntg) {
    constexpr int NT = EDIM / 32;          // 32 K-tiles
    __shared__ __align__(16) _Float16 S[3][8192];   // [buf][A 4096 | B 4096]

    const int tid  = threadIdx.x;
    const int xcd  = blockIdx.x & 7;
    const int slot = blockIdx.x >> 3;
    const int mg   = slot / ntg;
    const int nn   = slot - mg * ntg;
    const int m0   = (xcd + mg * 8) * 128;
    const int n0   = nn * 128;

    const int w = tid >> 6, lane = tid & 63;
    const int wr = w >> 1, wc = w & 1;         // 2x2 waves of 64x64
    const int lrow = lane & 15, lquad = lane >> 4;

    floatx4 acc[4][4] = {};

    // staging: thread t -> row r0 = t>>2 (call1: +64), chunk c0 = t&3.
    // LDS dest (lane-pinned) = (r0, c0); global chunk = c0 ^ ((r0>>1)&3).
    const int r0 = tid >> 2;                   // 0..63
    const int c0 = tid & 3;
    const int gk = (c0 ^ ((r0 >> 1) & 3)) * 8; // swizzled k-offset (halfs)
    const _Float16* Ag0 = A  + (size_t)(m0 + r0) * EDIM + gk;
    const _Float16* Ag1 = Ag0 + (size_t)64 * EDIM;
    const _Float16* Bg0 = Bt + (size_t)(n0 + r0) * EDIM + gk;
    const _Float16* Bg1 = Bg0 + (size_t)64 * EDIM;

    // read geometry: chunk xor depends only on lrow (rows step by 16)
    const int xr   = (lrow >> 1) & 3;
    const int koff = (lquad ^ xr) * 8;
    const int aoff = (wr * 64 + lrow) * 32 + koff;         // frag i adds i*512
    const int boff = 4096 + (wc * 64 + lrow) * 32 + koff;  // frag j adds j*512

    auto stage = [&](int buf, int kt) {
        _Float16* d = &S[buf][tid * 8];
        const int ko = kt * 32;
        gld_lds16(Ag0 + ko, d);
        gld_lds16(Ag1 + ko, d + 2048);
        gld_lds16(Bg0 + ko, d + 4096);
        gld_lds16(Bg1 + ko, d + 6144);
    };

    // prologue: stage tiles 0,1; wait tile 0 (tile 1's 4 loads may stay out)
    stage(0, 0);
    stage(1, 1);
    asm volatile("s_waitcnt vmcnt(4)" ::: "memory");
    __builtin_amdgcn_s_barrier();

    int buf = 0, sbuf = 2;                    // compute buffer / stage buffer
#pragma unroll 1
    for (int t = 0; t < NT; ++t) {
        const _Float16* Sb = S[buf];
        if (t + 2 < NT) stage(sbuf, t + 2);   // issue early (T3 recipe)

        half8 af[4], bf[4];
#pragma unroll
        for (int i = 0; i < 4; ++i) af[i] = *(const half8*)(Sb + aoff + i * 512);
#pragma unroll
        for (int j = 0; j < 4; ++j) bf[j] = *(const half8*)(Sb + boff + j * 512);

        __builtin_amdgcn_s_setprio(1);
#pragma unroll
        for (int i = 0; i < 4; ++i)
#pragma unroll
            for (int j = 0; j < 4; ++j)
                acc[i][j] = __builtin_amdgcn_mfma_f32_16x16x32_f16(
                    af[i], bf[j], acc[i][j], 0, 0, 0);
        __builtin_amdgcn_s_setprio(0);

        // tile boundary: counted wait -> tile t+1 resident; never drain to 0
        // in steady state (2 tiles = 8 loads in flight, keep <=4 = 1 tile).
        if (t < NT - 2)       asm volatile("s_waitcnt vmcnt(4)" ::: "memory");
        else if (t == NT - 2) asm volatile("s_waitcnt vmcnt(0)" ::: "memory");
        if (t < NT - 1) {
            asm volatile("" ::: "memory");
            __builtin_amdgcn_s_barrier();
            asm volatile("" ::: "memory");
        }
        buf  = (buf  == 2) ? 0 : buf + 1;
        sbuf = (sbuf == 2) ? 0 : sbuf + 1;
    }

    // Epilogue (unchanged, m89-verified C/D layout: col=lane&15, row=(lane>>4)*4+reg)
    const int cm = m0 + wr * 64 + lquad * 4;
    const int cn = n0 + wc * 64 + lrow;
#pragma unroll
    for (int j = 0; j < 4; ++j) {
        const int gn = cn + j * 16;
        float bv;
        if (MODE == 0) {
            bv = bias[gn];
        } else {
            // 16-aligned col groups; NTRI, NTRI+64 are multiples of 16
            if (gn < NTRI)             bv = bias[gn];
            else if (gn < NTRI + VDIM) bv = bias2[gn - NTRI];
            else                       bv = 0.0f;
        }
#pragma unroll
        for (int i = 0; i < 4; ++i) {
#pragma unroll
            for (int r = 0; r < 4; ++r) {
                float x = acc[i][j][r] + bv;
                float y;
                if (MODE == 0) {
                    y = 0.5f * x * (1.0f + fast_erf(x * 0.70710678118654752f));
                } else {
                    if (gn < NTRI)             y = fast_softplus(x);
                    else if (gn < NTRI + VDIM) y = x;      // raw pi logit
                    else                       y = 0.0f;   // padding
                }
                C[(size_t)(cm + i * 16 + r) * ldC + gn] = (_Float16)y;
            }
        }
    }
}

// ---------------- LayerNorm: fp16 G in -> fp16 Hh out ----------------
__global__ __launch_bounds__(256) void ln_kernel(const _Float16* __restrict__ G,
                                                 const float* __restrict__ gw,
                                                 const float* __restrict__ bw,
                                                 _Float16* __restrict__ Hh) {
    const int row = blockIdx.x, tid = threadIdx.x;
    half4v v = ((const half4v*)(G + (size_t)row * EDIM))[tid];
    float x0 = (float)v[0], x1 = (float)v[1], x2 = (float)v[2], x3 = (float)v[3];
    float s  = x0 + x1 + x2 + x3;
    float ss = x0 * x0 + x1 * x1 + x2 * x2 + x3 * x3;
#pragma unroll
    for (int off = 32; off; off >>= 1) {
        s  += __shfl_down(s, off);
        ss += __shfl_down(ss, off);
    }
    __shared__ float red[8];
    const int w = tid >> 6, lane = tid & 63;
    if (lane == 0) { red[w] = s; red[4 + w] = ss; }
    __syncthreads();
    const float st  = red[0] + red[1] + red[2] + red[3];
    const float sst = red[4] + red[5] + red[6] + red[7];
    const float mu  = st * (1.0f / EDIM);
    const float rs  = 1.0f / sqrtf(sst * (1.0f / EDIM) - mu * mu + 1e-5f);
    float4 gg = ((const float4*)gw)[tid];
    float4 bb = ((const float4*)bw)[tid];
    half4v h4;
    h4[0] = (_Float16)((x0 - mu) * rs * gg.x + bb.x);
    h4[1] = (_Float16)((x1 - mu) * rs * gg.y + bb.y);
    h4[2] = (_Float16)((x2 - mu) * rs * gg.z + bb.z);
    h4[3] = (_Float16)((x3 - mu) * rs * gg.w + bb.w);
    ((half4v*)(Hh + (size_t)row * EDIM))[tid] = h4;
}

// ---------------- Q build + fused softmax: one block per (b,l) row ---------
__global__ __launch_bounds__(256) void q_kernel(const _Float16* __restrict__ Theta,
                                                float* __restrict__ pi_out,
                                                float* __restrict__ Q) {
    const int row = blockIdx.x;
    const int tid = threadIdx.x;
    __shared__ float Th[NTRI];
    __shared__ float spv[VDIM];
    const _Float16* trow = Theta + (size_t)row * NTC;
    if (tid < 252) {  // 252 * 8 = 2016 = NTRI exactly
        half8 h = *(const half8*)(trow + tid * 8);
#pragma unroll
        for (int u = 0; u < 8; ++u) Th[tid * 8 + u] = (float)h[u];
    }
    if (tid >= 192) {  // wave 3: softmax over the 64 logits
        const int lane = tid & 63;
        float lg = (float)trow[NTRI + lane];
        float m = lg;
#pragma unroll
        for (int off = 32; off; off >>= 1) m = fmaxf(m, __shfl_xor(m, off));
        float e = __expf(lg - m);
        float ssum = e;
#pragma unroll
        for (int off = 32; off; off >>= 1) ssum += __shfl_xor(ssum, off);
        float p = e / ssum;
        pi_out[(size_t)row * VDIM + lane] = p;
        spv[lane] = sqrtf(p);
    }
    __syncthreads();

    const int i = tid >> 2;   // Q row 0..63
    const int q = tid & 3;    // col quarter
    const float rpi = 1.0f / spv[i];
    float vals[16];
    float psum = 0.f;
#pragma unroll
    for (int c = 0; c < 16; ++c) {
        const int j = q * 16 + c;
        float out = 0.f;
        if (j != i) {
            const int a = (i < j) ? i : j;
            const int b = (i < j) ? j : i;
            const int t = a * (127 - a) / 2 + (b - a - 1);
            out = Th[t] * spv[j] * rpi;
            psum += out;
        }
        vals[c] = out;
    }
    psum += __shfl_xor(psum, 1);
    psum += __shfl_xor(psum, 2);
    if ((i >> 4) == q) vals[i & 15] = -psum;   // fold diagonal into the store

    float* qrow = Q + ((size_t)row * VDIM + i) * VDIM + q * 16;
    float4* dst = (float4*)qrow;
    dst[0] = make_float4(vals[0], vals[1], vals[2], vals[3]);
    dst[1] = make_float4(vals[4], vals[5], vals[6], vals[7]);
    dst[2] = make_float4(vals[8], vals[9], vals[10], vals[11]);
    dst[3] = make_float4(vals[12], vals[13], vals[14], vals[15]);
}

// ---------------- orchestration ----------------
extern "C" void kernel_launch(void* const* d_in, const int* in_sizes, int n_in,
                              void* d_out, int out_size, void* d_ws, size_t ws_size,
                              hipStream_t stream) {
    const float* hx      = (const float*)d_in[0];
    const float* W_dense = (const float*)d_in[1];
    const float* b_dense = (const float*)d_in[2];
    const float* ln_g    = (const float*)d_in[3];
    const float* ln_b    = (const float*)d_in[4];
    const float* W_theta = (const float*)d_in[5];
    const float* b_theta = (const float*)d_in[6];
    const float* W_Theta = (const float*)d_in[7];
    const float* b_Theta = (const float*)d_in[8];

    uint8_t* ws = (uint8_t*)d_ws;
    _Float16* A_h  = (_Float16*)ws;                          // 16 MB (hx fp16; later h fp16)
    _Float16* Wd_h = (_Float16*)(ws + (size_t)16 * 1048576); //  2 MB
    _Float16* Wc_h = (_Float16*)(ws + (size_t)18 * 1048576); //  4.25 MB (2176x1024)
    _Float16* G_h  = (_Float16*)(ws + (size_t)23 * 1048576); // 16 MB (gelu out, fp16)
    _Float16* Th_h = (_Float16*)(ws + (size_t)23 * 1048576); // 35.7 MB (8192x2176 fp16)

    float* Q_out  = (float*)d_out;                 // 8192*64*64
    float* pi_out = (float*)d_out + (size_t)MROWS * VDIM * VDIM;

    // 1) all fp32->fp16 casts in ONE kernel (8192 + 1024 + 2176 blocks)
    cast_all<<<11392, 256, 0, stream>>>(hx, W_dense, W_Theta, W_theta,
                                        A_h, Wd_h, Wc_h);

    // 2) dense GEMM + gelu -> G_h.  128x128 tiles: 64m x 8n = 512 blocks
    gemm128<0><<<512, 256, 0, stream>>>(A_h, Wd_h, b_dense, nullptr, G_h, EDIM, 8);

    // 3) LayerNorm: fp16 G -> fp16 h into A_h
    ln_kernel<<<MROWS, 256, 0, stream>>>(G_h, ln_g, ln_b, A_h);

    // 4) theta GEMM (all 17 n-tiles, one kernel): 64m x 17n = 1088 blocks
    gemm128<1><<<1088, 256, 0, stream>>>(A_h, Wc_h, b_Theta, b_theta, Th_h, NTC, 17);

    // 5) Q assembly + fused softmax
    q_kernel<<<MROWS, 256, 0, stream>>>(Th_h, pi_out, Q_out);
}